// Round 4
// baseline (314.612 us; speedup 1.0000x reference)
//
#include <hip/hip_runtime.h>
#include <hip/hip_bf16.h>
#include <stdint.h>

// CirculantLinear == dense GEMM: y[b,o] = sum_n x[b,n]*rows[o,n] + bias[o]
// where rows[o,n] = c[o, (4096-n) & 4095].
// M=8192 (B), N=4096 (OUT), K=4096 (IN). fp32 in/out, bf16 MFMA inside.
// GEMM: 256x256 tile, BK=64, 8 waves, 8-phase counted-vmcnt schedule
// (T2 swizzle + T3/T4 counted vmcnt + T5 setprio per the m201 template).
// R3: T2 swizzle fixed to XOR (row>>1)&3 -> conflicts 2.5e7 -> 0.
// R4: MFMA shape 16x16x32 -> 32x32x16 (ceiling 2075 -> 2382+ TF, half the
//     MFMA instruction count, same LDS traffic); fused conversion kernels.

#define B_DIM  8192
#define OUT_DIM 4096
#define IN_DIM  4096
#define BK 64
#define NT (IN_DIM / BK)   // 64 K-tiles

typedef __attribute__((ext_vector_type(8))) short bf16x8;
typedef __attribute__((ext_vector_type(16))) float f32x16;
typedef __attribute__((ext_vector_type(8))) unsigned short u16x8;

__device__ __forceinline__ unsigned short f2bf(float f) {
  unsigned u = __float_as_uint(f);
  return (unsigned short)((u + 0x7fffu + ((u >> 16) & 1u)) >> 16);
}

// ---- fused conversion kernel --------------------------------------------

#define XCHUNKS (B_DIM * IN_DIM / 8 / 256)     // 16384 blocks for x
#define RCHUNKS (OUT_DIM * IN_DIM / 8 / 256)   // 8192 blocks for rows

__global__ void cvt_fused_kernel(const float* __restrict__ x,
                                 const float* __restrict__ c,
                                 unsigned short* __restrict__ xb,
                                 unsigned short* __restrict__ rb) {
  int b = blockIdx.x;
  if (b < XCHUNKS) {
    size_t i = ((size_t)b * 256 + threadIdx.x) * 8;
    const float4* p = (const float4*)(x + i);
    float4 a = p[0];
    float4 q = p[1];
    u16x8 o;
    o[0] = f2bf(a.x); o[1] = f2bf(a.y); o[2] = f2bf(a.z); o[3] = f2bf(a.w);
    o[4] = f2bf(q.x); o[5] = f2bf(q.y); o[6] = f2bf(q.z); o[7] = f2bf(q.w);
    *(u16x8*)(xb + i) = o;
  } else {
    int idx = (b - XCHUNKS) * 256 + threadIdx.x;
    int o  = idx >> 9;
    int n0 = (idx & 511) << 3;
    const float* crow = c + (size_t)o * IN_DIM;
    u16x8 v;
#pragma unroll
    for (int j = 0; j < 8; ++j) {
      int n = n0 + j;
      int s = (IN_DIM - n) & (IN_DIM - 1);
      v[j] = f2bf(crow[s]);
    }
    *(u16x8*)(rb + (size_t)o * IN_DIM + n0) = v;
  }
}

// ---- GEMM ---------------------------------------------------------------

__device__ __forceinline__ void async_copy16(const void* g, void* l) {
  __builtin_amdgcn_global_load_lds(
      (const __attribute__((address_space(1))) void*)g,
      (__attribute__((address_space(3))) void*)l, 16, 0, 0);
}

#define SMEM_BUF 65536  // per double-buffer half: A[2 kh][256][32] + B[2 kh][256][32]

// LDS physical layout per buffer: [A kh0 16K][A kh1 16K][B kh0 16K][B kh1 16K]
// Within a 16K khalf: row-major [256 r][32 c] bf16, 64 B/row (4 16B chunks),
// chunk-XOR swizzle: phys_chunk = logical_chunk ^ ((row>>1)&3).
// Frag read (32x32x16): row = base32 + (l&31), logical chunk (ks<<1)|(l>>5);
// every aligned 8-lane group covers all 8 bank quads -> conflict-free.
// Stage side applies the inverse via the per-lane GLOBAL source address
// (LDS dest stays linear for global_load_lds).

template<int BUF, int KK, int MH, int SMAT, int SBUF, int SKK, int SOFF, int VM>
__device__ __forceinline__ void phase(char* smem, int aRd, int bRd, int w,
                                      const unsigned short* sA,
                                      const unsigned short* sB,
                                      bf16x8 (*bF)[2], bf16x8 (*aF)[2],
                                      f32x16 (*acc)[2]) {
  const char* base = smem + BUF * SMEM_BUF + KK * 16384;
  // kstep0 phys chunk offset is baked into aRd/bRd; kstep1 = XOR 32.
  if (MH == 0) {
#pragma unroll
    for (int nb = 0; nb < 2; ++nb)
#pragma unroll
      for (int ks = 0; ks < 2; ++ks)
        bF[nb][ks] = *(const bf16x8*)(base + 32768 + (bRd ^ (ks * 32)) + nb * 2048);
#pragma unroll
    for (int mb = 0; mb < 2; ++mb)
#pragma unroll
      for (int ks = 0; ks < 2; ++ks)
        aF[mb][ks] = *(const bf16x8*)(base + (aRd ^ (ks * 32)) + mb * 2048);
  } else {
#pragma unroll
    for (int mb = 0; mb < 2; ++mb)
#pragma unroll
      for (int ks = 0; ks < 2; ++ks)
        aF[mb][ks] = *(const bf16x8*)(base + (aRd ^ (ks * 32)) + (2 + mb) * 2048);
  }
  if (SMAT >= 0) {
    const unsigned short* src = (SMAT ? sB : sA) + SOFF;
    char* dst = smem + SBUF * SMEM_BUF + SMAT * 32768 + SKK * 16384 + w * 1024;
    async_copy16(src, dst);                        // rows 0..127 of khalf
    async_copy16(src + 128 * IN_DIM, dst + 8192);  // rows 128..255
  }
  __builtin_amdgcn_s_barrier();
  asm volatile("s_waitcnt lgkmcnt(0)" ::: "memory");
  __builtin_amdgcn_sched_barrier(0);   // rule #18: fence MFMA behind the wait
  __builtin_amdgcn_s_setprio(1);
#pragma unroll
  for (int ks = 0; ks < 2; ++ks)
#pragma unroll
    for (int mb = 0; mb < 2; ++mb)
#pragma unroll
      for (int nb = 0; nb < 2; ++nb)
        acc[MH * 2 + mb][nb] = __builtin_amdgcn_mfma_f32_32x32x16_bf16(
            aF[mb][ks], bF[nb][ks], acc[MH * 2 + mb][nb], 0, 0, 0);
  __builtin_amdgcn_s_setprio(0);
  if (VM == 4) asm volatile("s_waitcnt vmcnt(4)" ::: "memory");
  if (VM == 0) asm volatile("s_waitcnt vmcnt(0)" ::: "memory");
  __builtin_amdgcn_s_barrier();
}

__global__ __launch_bounds__(512, 2) void gemm_kernel(
    const unsigned short* __restrict__ xb,   // [8192][4096] bf16
    const unsigned short* __restrict__ rb,   // [4096][4096] bf16 (rows)
    const float* __restrict__ bias,          // [4096]
    float* __restrict__ out) {               // [8192][4096] fp32
  __shared__ __align__(16) char smem[2 * SMEM_BUF];  // 128 KiB

  const int tid = threadIdx.x;
  const int w = tid >> 6, l = tid & 63;
  const int wr = w >> 2, wc = w & 3;       // 2 x 4 wave grid, wave owns 128x64

  // bijective XCD swizzle: 512 blocks = 8 XCDs x 64
  const int orig = blockIdx.x;
  const int wg = (orig & 7) * 64 + (orig >> 3);
  const int bm = (wg >> 4) * 256;          // 32 M-tiles
  const int bn = (wg & 15) * 256;          // 16 N-tiles

  // staging: thread t covers phys LDS bytes [t*16, t*16+16) of each 8K chunk.
  // phys row r = 16w + (l>>2) (+128 for 2nd copy; (r>>1)&3 = (l>>3)&3 both);
  // phys chunk = l&3; stored logical chunk = (l&3) ^ ((l>>3)&3).
  const int sgr = w * 16 + (l >> 2);
  const int sgc = ((l & 3) ^ ((l >> 3) & 3)) << 3;
  const unsigned short* sA = xb + (size_t)(bm + sgr) * IN_DIM + sgc;
  const unsigned short* sB = rb + (size_t)(bn + sgr) * IN_DIM + sgc;

  // frag reads (32x32x16): row = base32 + (l&31); logical chunk (ks<<1)|(l>>5)
  //   -> phys chunk = ((ks<<1)|(l>>5)) ^ ((l>>1)&3);  ks=1 is XOR 32 on bytes.
  const int swz = ((l >> 5) ^ ((l >> 1) & 3)) << 4;
  const int aRd = (wr * 128 + (l & 31)) * 64 + swz;
  const int bRd = (wc * 64 + (l & 31)) * 64 + swz;

  f32x16 acc[4][2];
#pragma unroll
  for (int i = 0; i < 4; ++i)
#pragma unroll
    for (int j = 0; j < 2; ++j)
#pragma unroll
      for (int e = 0; e < 16; ++e) acc[i][j][e] = 0.f;
  bf16x8 aF[2][2], bF[2][2];

  // ---- prologue: stage K-tile 0 into buf0 (order: A-kh0, B-kh0, A-kh1, B-kh1)
  {
    async_copy16(sA,                smem + 0 + w * 1024);
    async_copy16(sA + 128 * IN_DIM, smem + 0 + 8192 + w * 1024);
    async_copy16(sB,                smem + 32768 + w * 1024);
    async_copy16(sB + 128 * IN_DIM, smem + 32768 + 8192 + w * 1024);
    async_copy16(sA + 32,                smem + 16384 + w * 1024);
    async_copy16(sA + 32 + 128 * IN_DIM, smem + 16384 + 8192 + w * 1024);
    async_copy16(sB + 32,                smem + 32768 + 16384 + w * 1024);
    async_copy16(sB + 32 + 128 * IN_DIM, smem + 32768 + 16384 + 8192 + w * 1024);
  }
  sA += BK; sB += BK;   // now pointing at K-tile 1 (first to stage in loop)
  asm volatile("s_waitcnt vmcnt(4)" ::: "memory");  // kh0 A+B landed
  __builtin_amdgcn_s_barrier();

  // ---- main loop: 2 K-tiles per iteration, kt = 0..61
  for (int it = 0; it < 31; ++it) {
    // kt even: compute buf0, stage kt+1 -> buf1
    phase<0,0,0,  0,1,0,  0, -1>(smem, aRd, bRd, w, sA, sB, bF, aF, acc);
    phase<0,0,1,  1,1,0,  0,  4>(smem, aRd, bRd, w, sA, sB, bF, aF, acc);
    phase<0,1,0,  0,1,1, 32, -1>(smem, aRd, bRd, w, sA, sB, bF, aF, acc);
    phase<0,1,1,  1,1,1, 32,  4>(smem, aRd, bRd, w, sA, sB, bF, aF, acc);
    // kt odd: compute buf1, stage kt+2 -> buf0
    phase<1,0,0,  0,0,0, 64, -1>(smem, aRd, bRd, w, sA, sB, bF, aF, acc);
    phase<1,0,1,  1,0,0, 64,  4>(smem, aRd, bRd, w, sA, sB, bF, aF, acc);
    phase<1,1,0,  0,0,1, 96, -1>(smem, aRd, bRd, w, sA, sB, bF, aF, acc);
    phase<1,1,1,  1,0,1, 96,  4>(smem, aRd, bRd, w, sA, sB, bF, aF, acc);
    sA += 2 * BK; sB += 2 * BK;
  }
  // kt=62: compute buf0, stage kt63 -> buf1
  phase<0,0,0,  0,1,0,  0, -1>(smem, aRd, bRd, w, sA, sB, bF, aF, acc);
  phase<0,0,1,  1,1,0,  0,  4>(smem, aRd, bRd, w, sA, sB, bF, aF, acc);
  phase<0,1,0,  0,1,1, 32, -1>(smem, aRd, bRd, w, sA, sB, bF, aF, acc);
  phase<0,1,1,  1,1,1, 32,  4>(smem, aRd, bRd, w, sA, sB, bF, aF, acc);
  // kt=63: compute buf1, no staging; drain kh1 before its phase-3/4 reads
  phase<1,0,0, -1,0,0,  0, -1>(smem, aRd, bRd, w, sA, sB, bF, aF, acc);
  phase<1,0,1, -1,0,0,  0,  0>(smem, aRd, bRd, w, sA, sB, bF, aF, acc);
  phase<1,1,0, -1,0,0,  0, -1>(smem, aRd, bRd, w, sA, sB, bF, aF, acc);
  phase<1,1,1, -1,0,0,  0, -1>(smem, aRd, bRd, w, sA, sB, bF, aF, acc);

  // ---- epilogue: 32x32 C/D layout (m74/m101-verified):
  //   col = lane&31, row = (reg&3) + 8*(reg>>2) + 4*(lane>>5)
  const float bv0 = bias[bn + wc * 64 + (l & 31)];
  const float bv1 = bias[bn + wc * 64 + 32 + (l & 31)];
#pragma unroll
  for (int mb = 0; mb < 4; ++mb) {
    const int rowbase = bm + wr * 128 + mb * 32 + 4 * (l >> 5);
#pragma unroll
    for (int nb = 0; nb < 2; ++nb) {
      const int col = bn + wc * 64 + nb * 32 + (l & 31);
      const float bv = nb ? bv1 : bv0;
      float* po = out + (size_t)rowbase * OUT_DIM + col;
#pragma unroll
      for (int q = 0; q < 4; ++q)
#pragma unroll
        for (int rr = 0; rr < 4; ++rr)
          po[(size_t)(q * 8 + rr) * OUT_DIM] = acc[mb][nb][q * 4 + rr] + bv;
    }
  }
}

// ---- host ---------------------------------------------------------------

extern "C" void kernel_launch(void* const* d_in, const int* in_sizes, int n_in,
                              void* d_out, int out_size, void* d_ws, size_t ws_size,
                              hipStream_t stream) {
  const float* x    = (const float*)d_in[0];
  const float* c    = (const float*)d_in[1];
  const float* bias = (const float*)d_in[2];
  float* out = (float*)d_out;

  const size_t xb_elems = (size_t)B_DIM * IN_DIM;
  const size_t rb_elems = (size_t)OUT_DIM * IN_DIM;
  if (ws_size < (xb_elems + rb_elems) * sizeof(unsigned short)) return;

  unsigned short* xb = (unsigned short*)d_ws;
  unsigned short* rb = xb + xb_elems;

  cvt_fused_kernel<<<XCHUNKS + RCHUNKS, 256, 0, stream>>>(x, c, xb, rb);

  const int grid = (B_DIM / 256) * (OUT_DIM / 256);  // 32*16 = 512
  gemm_kernel<<<grid, 512, 0, stream>>>(xb, rb, bias, out);
}

// Round 5
// 286.791 us; speedup vs baseline: 1.0970x; 1.0970x over previous
//
#include <hip/hip_runtime.h>
#include <hip/hip_bf16.h>
#include <stdint.h>

// CirculantLinear == dense GEMM: y[b,o] = sum_n x[b,n]*rows[o,n] + bias[o]
// where rows[o,n] = c[o, (4096-n) & 4095].
// M=8192 (B), N=4096 (OUT), K=4096 (IN). fp32 in/out, bf16 MFMA inside.
// GEMM: 256x256 tile, BK=64, 8 waves, 8-phase counted-vmcnt schedule.
// R3: T2 swizzle XOR (row>>1)&3 -> conflicts 2.5e7 -> 0.  (248 us GEMM)
// R4: 32x32x16 shape -> REGRESSED (conflicts back at 2.5e7) -> reverted.
// R5: drop explicit lgkmcnt(0)+sched_barrier(0); compiler emits counted
//     lgkmcnt so MFMA issue overlaps LDS read service within each phase.
//     (rule #18 fence only needed for inline-asm ds_reads; ours are not.)

#define B_DIM  8192
#define OUT_DIM 4096
#define IN_DIM  4096
#define BK 64
#define NT (IN_DIM / BK)   // 64 K-tiles

typedef __attribute__((ext_vector_type(8))) short bf16x8;
typedef __attribute__((ext_vector_type(4))) float f32x4;
typedef __attribute__((ext_vector_type(8))) unsigned short u16x8;

__device__ __forceinline__ unsigned short f2bf(float f) {
  unsigned u = __float_as_uint(f);
  return (unsigned short)((u + 0x7fffu + ((u >> 16) & 1u)) >> 16);
}

// ---- fused conversion kernel --------------------------------------------

#define XCHUNKS (B_DIM * IN_DIM / 8 / 256)     // 16384 blocks for x
#define RCHUNKS (OUT_DIM * IN_DIM / 8 / 256)   // 8192 blocks for rows

__global__ void cvt_fused_kernel(const float* __restrict__ x,
                                 const float* __restrict__ c,
                                 unsigned short* __restrict__ xb,
                                 unsigned short* __restrict__ rb) {
  int b = blockIdx.x;
  if (b < XCHUNKS) {
    size_t i = ((size_t)b * 256 + threadIdx.x) * 8;
    const float4* p = (const float4*)(x + i);
    float4 a = p[0];
    float4 q = p[1];
    u16x8 o;
    o[0] = f2bf(a.x); o[1] = f2bf(a.y); o[2] = f2bf(a.z); o[3] = f2bf(a.w);
    o[4] = f2bf(q.x); o[5] = f2bf(q.y); o[6] = f2bf(q.z); o[7] = f2bf(q.w);
    *(u16x8*)(xb + i) = o;
  } else {
    int idx = (b - XCHUNKS) * 256 + threadIdx.x;
    int o  = idx >> 9;
    int n0 = (idx & 511) << 3;
    const float* crow = c + (size_t)o * IN_DIM;
    u16x8 v;
#pragma unroll
    for (int j = 0; j < 8; ++j) {
      int n = n0 + j;
      int s = (IN_DIM - n) & (IN_DIM - 1);
      v[j] = f2bf(crow[s]);
    }
    *(u16x8*)(rb + (size_t)o * IN_DIM + n0) = v;
  }
}

// ---- GEMM ---------------------------------------------------------------

__device__ __forceinline__ void async_copy16(const void* g, void* l) {
  __builtin_amdgcn_global_load_lds(
      (const __attribute__((address_space(1))) void*)g,
      (__attribute__((address_space(3))) void*)l, 16, 0, 0);
}

#define SMEM_BUF 65536  // per double-buffer half: A[2 kh][256][32] + B[2 kh][256][32]

// LDS physical layout per buffer: [A kh0 16K][A kh1 16K][B kh0 16K][B kh1 16K]
// Within a 16K khalf: row-major [256 r][32 c] bf16, 64 B/row (4 16B chunks),
// chunk-XOR swizzle: phys_chunk = logical_chunk ^ ((row>>1)&3)  (measured: 0
// conflicts with the 16-row frag-read pattern). Stage side applies the
// inverse via the per-lane GLOBAL source address (LDS dest stays linear).

template<int BUF, int KK, int MH, int SMAT, int SBUF, int SKK, int SOFF, int VM>
__device__ __forceinline__ void phase(char* smem, int aRd, int bRd, int w,
                                      const unsigned short* sA,
                                      const unsigned short* sB,
                                      bf16x8* bF, bf16x8* aF,
                                      f32x4 (*acc)[4]) {
  const char* base = smem + BUF * SMEM_BUF + KK * 16384;
  if (MH == 0) {
#pragma unroll
    for (int ni = 0; ni < 4; ++ni)
      bF[ni] = *(const bf16x8*)(base + 32768 + bRd + ni * 1024);
#pragma unroll
    for (int mi = 0; mi < 4; ++mi)
      aF[mi] = *(const bf16x8*)(base + aRd + mi * 1024);
  } else {
#pragma unroll
    for (int mi = 0; mi < 4; ++mi)
      aF[mi] = *(const bf16x8*)(base + aRd + (4 + mi) * 1024);
  }
  if (SMAT >= 0) {
    const unsigned short* src = (SMAT ? sB : sA) + SOFF;
    char* dst = smem + SBUF * SMEM_BUF + SMAT * 32768 + SKK * 16384 + w * 1024;
    async_copy16(src, dst);                        // rows 0..127 of khalf
    async_copy16(src + 128 * IN_DIM, dst + 8192);  // rows 128..255
  }
  __builtin_amdgcn_s_barrier();
  // R5: no explicit lgkmcnt(0) drain here — the ds_reads above are
  // compiler-generated, so the compiler emits counted lgkmcnt before each
  // dependent MFMA, overlapping LDS service with MFMA issue.
  __builtin_amdgcn_s_setprio(1);
#pragma unroll
  for (int i = 0; i < 4; ++i)
#pragma unroll
    for (int ni = 0; ni < 4; ++ni)
      acc[MH * 4 + i][ni] = __builtin_amdgcn_mfma_f32_16x16x32_bf16(
          aF[i], bF[ni], acc[MH * 4 + i][ni], 0, 0, 0);
  __builtin_amdgcn_s_setprio(0);
  if (VM == 4) asm volatile("s_waitcnt vmcnt(4)" ::: "memory");
  if (VM == 0) asm volatile("s_waitcnt vmcnt(0)" ::: "memory");
  __builtin_amdgcn_s_barrier();
}

__global__ __launch_bounds__(512, 2) void gemm_kernel(
    const unsigned short* __restrict__ xb,   // [8192][4096] bf16
    const unsigned short* __restrict__ rb,   // [4096][4096] bf16 (rows)
    const float* __restrict__ bias,          // [4096]
    float* __restrict__ out) {               // [8192][4096] fp32
  __shared__ __align__(16) char smem[2 * SMEM_BUF];  // 128 KiB

  const int tid = threadIdx.x;
  const int w = tid >> 6, l = tid & 63;
  const int wr = w >> 2, wc = w & 3;       // 2 x 4 wave grid, wave owns 128x64

  // bijective XCD swizzle: 512 blocks = 8 XCDs x 64
  const int orig = blockIdx.x;
  const int wg = (orig & 7) * 64 + (orig >> 3);
  const int bm = (wg >> 4) * 256;          // 32 M-tiles
  const int bn = (wg & 15) * 256;          // 16 N-tiles

  // staging: thread t covers phys LDS bytes [t*16, t*16+16) of each 8K chunk.
  // phys row r = 16w + (l>>2)  (+128 for second copy; both keep (r>>1)&3 =
  // (l>>3)&3);  phys chunk = l&3;
  // logical (global) chunk = phys ^ ((r>>1)&3) = (l&3) ^ ((l>>3)&3).
  const int sgr = w * 16 + (l >> 2);
  const int sgc = ((l & 3) ^ ((l >> 3) & 3)) << 3;
  const unsigned short* sA = xb + (size_t)(bm + sgr) * IN_DIM + sgc;
  const unsigned short* sB = rb + (size_t)(bn + sgr) * IN_DIM + sgc;

  // frag reads: row = 16-aligned base + (l&15), logical chunk (l>>4)
  //   -> phys chunk = (l>>4) ^ ((row>>1)&3) = (l>>4) ^ ((l>>1)&3)
  const int swz = ((l >> 4) ^ ((l >> 1) & 3)) << 4;
  const int aRd = (wr * 128 + (l & 15)) * 64 + swz;
  const int bRd = (wc * 64 + (l & 15)) * 64 + swz;

  f32x4 acc[8][4];
#pragma unroll
  for (int i = 0; i < 8; ++i)
#pragma unroll
    for (int j = 0; j < 4; ++j) acc[i][j] = (f32x4){0.f, 0.f, 0.f, 0.f};
  bf16x8 aF[4], bF[4];

  // ---- prologue: stage K-tile 0 into buf0 (order: A-kh0, B-kh0, A-kh1, B-kh1)
  {
    async_copy16(sA,                smem + 0 + w * 1024);
    async_copy16(sA + 128 * IN_DIM, smem + 0 + 8192 + w * 1024);
    async_copy16(sB,                smem + 32768 + w * 1024);
    async_copy16(sB + 128 * IN_DIM, smem + 32768 + 8192 + w * 1024);
    async_copy16(sA + 32,                smem + 16384 + w * 1024);
    async_copy16(sA + 32 + 128 * IN_DIM, smem + 16384 + 8192 + w * 1024);
    async_copy16(sB + 32,                smem + 32768 + 16384 + w * 1024);
    async_copy16(sB + 32 + 128 * IN_DIM, smem + 32768 + 16384 + 8192 + w * 1024);
  }
  sA += BK; sB += BK;   // now pointing at K-tile 1 (first to stage in loop)
  asm volatile("s_waitcnt vmcnt(4)" ::: "memory");  // kh0 A+B landed
  __builtin_amdgcn_s_barrier();

  // ---- main loop: 2 K-tiles per iteration, kt = 0..61
  for (int it = 0; it < 31; ++it) {
    // kt even: compute buf0, stage kt+1 -> buf1
    phase<0,0,0,  0,1,0,  0, -1>(smem, aRd, bRd, w, sA, sB, bF, aF, acc);
    phase<0,0,1,  1,1,0,  0,  4>(smem, aRd, bRd, w, sA, sB, bF, aF, acc);
    phase<0,1,0,  0,1,1, 32, -1>(smem, aRd, bRd, w, sA, sB, bF, aF, acc);
    phase<0,1,1,  1,1,1, 32,  4>(smem, aRd, bRd, w, sA, sB, bF, aF, acc);
    // kt odd: compute buf1, stage kt+2 -> buf0
    phase<1,0,0,  0,0,0, 64, -1>(smem, aRd, bRd, w, sA, sB, bF, aF, acc);
    phase<1,0,1,  1,0,0, 64,  4>(smem, aRd, bRd, w, sA, sB, bF, aF, acc);
    phase<1,1,0,  0,0,1, 96, -1>(smem, aRd, bRd, w, sA, sB, bF, aF, acc);
    phase<1,1,1,  1,0,1, 96,  4>(smem, aRd, bRd, w, sA, sB, bF, aF, acc);
    sA += 2 * BK; sB += 2 * BK;
  }
  // kt=62: compute buf0, stage kt63 -> buf1
  phase<0,0,0,  0,1,0,  0, -1>(smem, aRd, bRd, w, sA, sB, bF, aF, acc);
  phase<0,0,1,  1,1,0,  0,  4>(smem, aRd, bRd, w, sA, sB, bF, aF, acc);
  phase<0,1,0,  0,1,1, 32, -1>(smem, aRd, bRd, w, sA, sB, bF, aF, acc);
  phase<0,1,1,  1,1,1, 32,  4>(smem, aRd, bRd, w, sA, sB, bF, aF, acc);
  // kt=63: compute buf1, no staging; drain kh1 before its phase-3/4 reads
  phase<1,0,0, -1,0,0,  0, -1>(smem, aRd, bRd, w, sA, sB, bF, aF, acc);
  phase<1,0,1, -1,0,0,  0,  0>(smem, aRd, bRd, w, sA, sB, bF, aF, acc);
  phase<1,1,0, -1,0,0,  0, -1>(smem, aRd, bRd, w, sA, sB, bF, aF, acc);
  phase<1,1,1, -1,0,0,  0, -1>(smem, aRd, bRd, w, sA, sB, bF, aF, acc);

  // ---- epilogue: C/D layout col=lane&15, row=(lane>>4)*4+reg (m89-verified)
#pragma unroll
  for (int mi = 0; mi < 8; ++mi) {
    const int row = bm + wr * 128 + mi * 16 + (l >> 4) * 4;
#pragma unroll
    for (int ni = 0; ni < 4; ++ni) {
      const int col = bn + wc * 64 + ni * 16 + (l & 15);
      const float bv = bias[col];
      float* po = out + (size_t)row * OUT_DIM + col;
#pragma unroll
      for (int r2 = 0; r2 < 4; ++r2)
        po[(size_t)r2 * OUT_DIM] = acc[mi][ni][r2] + bv;
    }
  }
}

// ---- host ---------------------------------------------------------------

extern "C" void kernel_launch(void* const* d_in, const int* in_sizes, int n_in,
                              void* d_out, int out_size, void* d_ws, size_t ws_size,
                              hipStream_t stream) {
  const float* x    = (const float*)d_in[0];
  const float* c    = (const float*)d_in[1];
  const float* bias = (const float*)d_in[2];
  float* out = (float*)d_out;

  const size_t xb_elems = (size_t)B_DIM * IN_DIM;
  const size_t rb_elems = (size_t)OUT_DIM * IN_DIM;
  if (ws_size < (xb_elems + rb_elems) * sizeof(unsigned short)) return;

  unsigned short* xb = (unsigned short*)d_ws;
  unsigned short* rb = xb + xb_elems;

  cvt_fused_kernel<<<XCHUNKS + RCHUNKS, 256, 0, stream>>>(x, c, xb, rb);

  const int grid = (B_DIM / 256) * (OUT_DIM / 256);  // 32*16 = 512
  gemm_kernel<<<grid, 512, 0, stream>>>(xb, rb, bias, out);
}